// Round 7
// baseline (8407.969 us; speedup 1.0000x reference)
//
#include <hip/hip_runtime.h>
#include <hip/hip_bf16.h>

// GRU: L=2, B=32, T=1024, H=512, OUT=512
// Round 7: in-band LSB "written" tags; zero canaries, zero drains, zero atomics.
//   A (WG 0..15):  layer-0 spine. W_hh0 in regs. Stores h0all[t] as f16|1.
//   B (WG 16..31): layer-1. W_hh1 in regs + W_ih1 in LDS (swizzled). One
//                  combined retry burst loads h1(t-1) + h0(t); 96 MFMA; fuse.
// Safety: 16B loads/2B stores are LLC-atomic; T-deep buffers written once;
// k0 re-zeroes the tag regions every call (replay-safe). Dep graph acyclic.

typedef _Float16 f16x8 __attribute__((ext_vector_type(8)));
typedef float f32x4 __attribute__((ext_vector_type(4)));
typedef unsigned short u16;
typedef unsigned int u32;
typedef u32 u32x2 __attribute__((ext_vector_type(2)));
typedef u32 u32x4 __attribute__((ext_vector_type(4)));

#define MFMA16(a,b,c) __builtin_amdgcn_mfma_f32_16x16x32_f16((a),(b),(c),0,0,0)
#define SB0 __builtin_amdgcn_sched_barrier(0)
#define VMC0 asm volatile("s_waitcnt vmcnt(0)" ::: "memory")

static constexpr int B = 32, T = 1024, H = 512, G3 = 1536;

// ws layout (bytes)
static constexpr size_t OFF_GX  = 0;                               // 96MB f16 [t][g*512+u][b]
static constexpr size_t OFF_H0  = OFF_GX + (size_t)T*G3*B*2;       // 32MB f16|LSB [t][b][u]
static constexpr size_t OFF_H1  = OFF_H0 + (size_t)T*B*H*2;        // 32MB f16|LSB [t][b][u]
static constexpr size_t OFF_W0  = OFF_H1 + (size_t)T*B*H*2;        // 1.5MB f16
static constexpr size_t OFF_H0I = OFF_W0 + (size_t)G3*H*2;         // 32KB f16
static constexpr size_t OFF_H1I = OFF_H0I + (size_t)B*H*2;         // 32KB f16
static constexpr size_t OFF_H1F = OFF_H1I + (size_t)B*H*2;         // 64KB f32
static constexpr size_t ZERO_BYTES = OFF_W0 - OFF_H0;              // 64MB

__device__ __forceinline__ u16 f2h(float x){ _Float16 h=(_Float16)x; return __builtin_bit_cast(u16,h); }
__device__ __forceinline__ float h2f(u16 u){ _Float16 h=__builtin_bit_cast(_Float16,u); return (float)h; }

// ---- device-scope (LLC) primitives ----
__device__ __forceinline__ f16x8 llc_ld16(const u16* p){   // no wait
  f16x8 r; asm volatile("global_load_dwordx4 %0, %1, off sc0 sc1" : "=v"(r) : "v"(p)); return r;
}
__device__ __forceinline__ f16x8 pl_ld16(const u16* p){    // plain, no wait
  f16x8 r; asm volatile("global_load_dwordx4 %0, %1, off" : "=v"(r) : "v"(p)); return r;
}
__device__ __forceinline__ void llc_st16(u16* p, u32 v){
  asm volatile("global_store_short %0, %1, off sc0 sc1" :: "v"(p), "v"(v) : "memory");
}

__device__ __forceinline__ float fsig(float x){ return 1.f/(1.f+__expf(-x)); }
__device__ __forceinline__ float ftanh(float x){
  x = fminf(15.f, fmaxf(-15.f, x));
  float e = __expf(-2.f*x);
  return (1.f-e)/(1.f+e);
}
__device__ __forceinline__ float gxval(u32x2 g, int j){
  u32 w = (j & 2) ? g[1] : g[0];
  return h2f((u16)(w >> ((j & 1) * 16)));
}
__device__ __forceinline__ u32 lsb_acc(f16x8 v){
  u32x4 w = __builtin_bit_cast(u32x4, v);
  return w[0] & w[1] & w[2] & w[3];
}

// W fragments (f32 -> f16) into registers; rows gate*512+cu, cols kk*32+lk*8
__device__ __forceinline__ void load_wf(f16x8 (*wf)[16], const float* Wbase, int cu, int lk){
#pragma unroll
  for (int g=0; g<3; g++)
#pragma unroll
    for (int kk=0; kk<16; kk++){
      const float* s = Wbase + ((size_t)(g*512 + cu))*H + kk*32 + lk*8;
      f32x4 s0 = *(const f32x4*)s, s1 = *(const f32x4*)(s+4);
      f16x8 v;
#pragma unroll
      for (int e=0; e<4; e++){ v[e]=(_Float16)s0[e]; v[4+e]=(_Float16)s1[e]; }
      wf[g][kk] = v;
    }
}
// MFMA B-operand fragment from XOR-swizzled LDS weights [96 rows][512] f16
__device__ __forceinline__ f16x8 lds_frag(const u16* wlds, int lrbase, int l15, int lk, int kk){
  int lr = lrbase + l15;
  int byte = lr*1024 + (((((kk<<5)+(lk<<3))<<1)) ^ ((lr&7)<<4));
  return *(const f16x8*)((const char*)wlds + byte);
}

// ---------------- k0: prep ----------------
__global__ __launch_bounds__(256) void k0_prep(const float* __restrict__ wih,
                                               const float* __restrict__ h0in,
                                               u16* __restrict__ wih0f16,
                                               u16* __restrict__ h0i,
                                               u16* __restrict__ h1i,
                                               u32x4* __restrict__ zbase){
  int i = blockIdx.x*256 + threadIdx.x;                  // 65536 threads
  const int NZ = (int)(ZERO_BYTES / 16);
  u32x4 z; z[0]=0; z[1]=0; z[2]=0; z[3]=0;
  for (int idx=i; idx<NZ; idx+=65536) zbase[idx] = z;
  for (int idx=i; idx<G3*H; idx+=65536) wih0f16[idx] = f2h(wih[idx]);
  if (i < B*H){ h0i[i] = f2h(h0in[i]); h1i[i] = f2h(h0in[B*H + i]); }
}

// ---------------- k1: gx0 GEMM  (out [t][gate][u][b] f16) ----------------
__global__ __launch_bounds__(256) void k1_gx(const float* __restrict__ x,
                                             const u16* __restrict__ wih0,
                                             const float* __restrict__ bih0,
                                             u16* __restrict__ gxT){
  int t  = blockIdx.x / 6, nb = blockIdx.x % 6;
  int wave = threadIdx.x >> 6, lane = threadIdx.x & 63;
  int l15 = lane & 15, lk = lane >> 4;
  int colbase = nb*256 + wave*64;
  f32x4 acc[2][4] = {};
#pragma unroll 4
  for (int kk=0; kk<16; kk++){
    int k0 = kk*32 + lk*8;
    f16x8 a[2];
#pragma unroll
    for (int bm=0; bm<2; bm++){
      const f32x4* xp_ = (const f32x4*)(x + ((size_t)(bm*16+l15)*T + t)*H + k0);
      f32x4 x0 = xp_[0], x1 = xp_[1];
      f16x8 v;
#pragma unroll
      for (int q=0;q<4;q++){ v[q]=(_Float16)x0[q]; v[4+q]=(_Float16)x1[q]; }
      a[bm] = v;
    }
#pragma unroll
    for (int nt=0; nt<4; nt++){
      int col = colbase + nt*16 + l15;
      f16x8 bf = *(const f16x8*)(wih0 + (size_t)col*H + k0);
      acc[0][nt] = MFMA16(a[0], bf, acc[0][nt]);
      acc[1][nt] = MFMA16(a[1], bf, acc[1][nt]);
    }
  }
#pragma unroll
  for (int nt=0; nt<4; nt++){
    int col = colbase + nt*16 + l15;
    float bias = bih0[col];
#pragma unroll
    for (int bm=0; bm<2; bm++){
      u32 lo = (u32)f2h(acc[bm][nt][0]+bias) | ((u32)f2h(acc[bm][nt][1]+bias) << 16);
      u32 hi = (u32)f2h(acc[bm][nt][2]+bias) | ((u32)f2h(acc[bm][nt][3]+bias) << 16);
      u32x2 v; v[0]=lo; v[1]=hi;
      *(u32x2*)(gxT + ((size_t)t*G3 + col)*B + bm*16 + lk*4) = v;
    }
  }
}

// ---------------- k2: persistent recurrence (32 WGs) ----------------
__global__ __launch_bounds__(256,1) void k2_recur(const float* __restrict__ h0in,
    const float* __restrict__ Wih, const float* __restrict__ bih,
    const float* __restrict__ Whh, const float* __restrict__ bhh,
    const u16* __restrict__ gxT,
    u16* __restrict__ h0all, u16* __restrict__ h1all,
    const u16* __restrict__ h0i, const u16* __restrict__ h1i,
    float* __restrict__ h1fin)
{
  __shared__ u16 wlds[96*512];
  const int wg = blockIdx.x, tid = threadIdx.x;
  const int wave = tid >> 6, lane = tid & 63;
  const int l15 = lane & 15, lk = lane >> 4;
  const int bm = wave >> 1, ug = wave & 1;
  const u32 M = 0x00010001u;

  if (wg < 16){
    // ================= A: layer-0 spine =================
    const int slot = wg;
    const int cu   = slot*32 + ug*16 + l15;
    f16x8 wf[3][16]; load_wf(wf, Whh, cu, lk);
    const float bhr = bhh[cu], bhu = bhh[512+cu], bhn = bhh[1024+cu];
    float hown[4];
#pragma unroll
    for (int j=0;j<4;j++) hown[j] = h0in[(size_t)(bm*16+lk*4+j)*H + cu];

    // gx(0) prologue (drained by first VMC0 below)
    u32x2 g0, g1, g2;
    { const u16* gp = gxT + ((size_t)0*G3 + cu)*B + bm*16 + lk*4;
      g0 = *(const u32x2*)gp; g1 = *(const u32x2*)(gp + (size_t)512*B);
      g2 = *(const u32x2*)(gp + (size_t)1024*B); }

    for (int t=0; t<T; t++){
      f16x8 af[16];
      if (t == 0){
        const u16* hr = h0i + (size_t)(bm*16+l15)*H + lk*8;
#pragma unroll
        for (int kk=0; kk<16; kk++) af[kk] = pl_ld16(hr + kk*32);
        VMC0; SB0;
      } else {
        const u16* hr = h0all + ((size_t)(t-1)*B + bm*16 + l15)*H + lk*8;
        for (;;){
#pragma unroll
          for (int kk=0; kk<16; kk++) af[kk] = llc_ld16(hr + kk*32);
          VMC0; SB0;
          u32 acc = M;
#pragma unroll
          for (int kk=0; kk<16; kk++) acc &= lsb_acc(af[kk]);
          if (__all((acc & M) == M)) break;
        }
      }
      f32x4 aR{}, aU{}, aN{};
#pragma unroll
      for (int kk=0; kk<16; kk++){
        aR = MFMA16(af[kk], wf[0][kk], aR);
        aU = MFMA16(af[kk], wf[1][kk], aU);
        aN = MFMA16(af[kk], wf[2][kk], aN);
      }
#pragma unroll
      for (int j=0;j<4;j++){
        float r = fsig(gxval(g0,j) + aR[j] + bhr);
        float u = fsig(gxval(g1,j) + aU[j] + bhu);
        float n = ftanh(gxval(g2,j) + r*(aN[j] + bhn));
        hown[j] = u*hown[j] + (1.f-u)*n;
        llc_st16(h0all + ((size_t)t*B + bm*16+lk*4+j)*H + cu,
                 (u32)(f2h(hown[j]) | 1u));              // in-band "written" tag
      }
      if (t+1 < T){                                       // gx prefetch (plain)
        const u16* gp = gxT + ((size_t)(t+1)*G3 + cu)*B + bm*16 + lk*4;
        g0 = *(const u32x2*)gp; g1 = *(const u32x2*)(gp + (size_t)512*B);
        g2 = *(const u32x2*)(gp + (size_t)1024*B);
      }
    }
  } else {
    // ================= B: layer-1 (h-side regs + x-side LDS) =================
    const int slot = wg - 16;
    // fill LDS with W_ih1 slice (96 rows x 512, XOR-swizzled), f32->f16
    for (int idx = tid; idx < 96*64; idx += 256){
      int lr = idx >> 6, k8 = idx & 63;
      int g = lr >> 5, uu = lr & 31;
      const float* src = Wih + (size_t)G3*H + ((size_t)(g*512 + slot*32 + uu))*H + k8*8;
      f32x4 s0=*(const f32x4*)src, s1=*(const f32x4*)(src+4);
      f16x8 v;
#pragma unroll
      for (int e=0;e<4;e++){ v[e]=(_Float16)s0[e]; v[4+e]=(_Float16)s1[e]; }
      *(f16x8*)((char*)wlds + lr*1024 + ((k8*16) ^ ((lr&7)<<4))) = v;
    }
    __syncthreads();

    const int cu = slot*32 + ug*16 + l15;
    f16x8 wfh[3][16]; load_wf(wfh, Whh + (size_t)G3*H, cu, lk);
    const float br  = bih[G3 + cu]       + bhh[G3 + cu];
    const float bu_ = bih[G3 + 512 + cu] + bhh[G3 + 512 + cu];
    const float bni = bih[G3 + 1024 + cu];
    const float bnh = bhh[G3 + 1024 + cu];
    float hown[4];
#pragma unroll
    for (int j=0;j<4;j++) hown[j] = h0in[(size_t)B*H + (size_t)(bm*16+lk*4+j)*H + cu];

    const size_t rowoff = (size_t)(bm*16 + l15)*H + lk*8;

    for (int t=0; t<T; t++){
      f16x8 ah[16], ax[16];
      const u16* xr = h0all + (size_t)t*(B*H) + rowoff;
      const u16* hr = (t==0) ? (h1i + rowoff)
                             : (h1all + (size_t)(t-1)*(B*H) + rowoff);
      for (;;){
        if (t == 0){
#pragma unroll
          for (int kk=0; kk<16; kk++) ah[kk] = pl_ld16(hr + kk*32);
        } else {
#pragma unroll
          for (int kk=0; kk<16; kk++) ah[kk] = llc_ld16(hr + kk*32);
        }
#pragma unroll
        for (int kk=0; kk<16; kk++) ax[kk] = llc_ld16(xr + kk*32);
        VMC0; SB0;
        u32 acc = M;
#pragma unroll
        for (int kk=0; kk<16; kk++) acc &= lsb_acc(ax[kk]);
        if (t > 0){
#pragma unroll
          for (int kk=0; kk<16; kk++) acc &= lsb_acc(ah[kk]);
        }
        if (__all((acc & M) == M)) break;
      }
      f32x4 hR{}, hU{}, hN{};
#pragma unroll
      for (int kk=0; kk<16; kk++){
        hR = MFMA16(ah[kk], wfh[0][kk], hR);
        hU = MFMA16(ah[kk], wfh[1][kk], hU);
        hN = MFMA16(ah[kk], wfh[2][kk], hN);
      }
      f32x4 xR{}, xU{}, xN{};
#pragma unroll
      for (int kk=0; kk<16; kk++){
        xR = MFMA16(ax[kk], lds_frag(wlds,      ug*16, l15, lk, kk), xR);
        xU = MFMA16(ax[kk], lds_frag(wlds, 32 + ug*16, l15, lk, kk), xU);
        xN = MFMA16(ax[kk], lds_frag(wlds, 64 + ug*16, l15, lk, kk), xN);
      }
#pragma unroll
      for (int j=0;j<4;j++){
        float r = fsig(xR[j] + hR[j] + br);
        float u = fsig(xU[j] + hU[j] + bu_);
        float n = ftanh(xN[j] + bni + r*(hN[j] + bnh));
        hown[j] = u*hown[j] + (1.f-u)*n;
        int b = bm*16 + lk*4 + j;
        llc_st16(h1all + (size_t)t*(B*H) + (size_t)b*H + cu,
                 (u32)(f2h(hown[j]) | 1u));
        if (t == T-1) h1fin[(size_t)b*H + cu] = hown[j];
      }
    }
  }
}

// ---------------- k3: FC ----------------
__global__ __launch_bounds__(256) void k3_fc(const float* __restrict__ h1fin,
                                             const float* __restrict__ fcW,
                                             const float* __restrict__ fcb,
                                             float* __restrict__ out){
  int g = blockIdx.x*256 + threadIdx.x;     // 16384
  int b = g >> 9, o = g & 511;
  const f32x4* w = (const f32x4*)(fcW + (size_t)o*H);
  const f32x4* h = (const f32x4*)(h1fin + (size_t)b*H);
  float acc = fcb[o];
#pragma unroll 4
  for (int k=0;k<128;k++){
    f32x4 wv = w[k], hv = h[k];
    acc += wv[0]*hv[0] + wv[1]*hv[1] + wv[2]*hv[2] + wv[3]*hv[3];
  }
  out[g] = acc;
}

extern "C" void kernel_launch(void* const* d_in, const int* in_sizes, int n_in,
                              void* d_out, int out_size, void* d_ws, size_t ws_size,
                              hipStream_t stream) {
  const float* x    = (const float*)d_in[0];
  const float* h0   = (const float*)d_in[1];
  const float* Wih  = (const float*)d_in[2];
  const float* bihv = (const float*)d_in[3];
  const float* Whh  = (const float*)d_in[4];
  const float* bhhv = (const float*)d_in[5];
  const float* fcW  = (const float*)d_in[6];
  const float* fcb  = (const float*)d_in[7];
  float* out = (float*)d_out;

  char* ws = (char*)d_ws;
  u16* gxT     = (u16*)(ws + OFF_GX);
  u16* h0all   = (u16*)(ws + OFF_H0);
  u16* h1all   = (u16*)(ws + OFF_H1);
  u16* wih0f16 = (u16*)(ws + OFF_W0);
  u16* h0i     = (u16*)(ws + OFF_H0I);
  u16* h1i     = (u16*)(ws + OFF_H1I);
  float* h1fin = (float*)(ws + OFF_H1F);

  k0_prep<<<256, 256, 0, stream>>>(Wih, h0, wih0f16, h0i, h1i, (u32x4*)(ws + OFF_H0));
  k1_gx<<<T*6, 256, 0, stream>>>(x, wih0f16, bihv, gxT);
  k2_recur<<<32, 256, 0, stream>>>(h0, Wih, bihv, Whh, bhhv, gxT,
                                   h0all, h1all, h0i, h1i, h1fin);
  k3_fc<<<64, 256, 0, stream>>>(h1fin, fcW, fcb, out);
}